// Round 14
// baseline (385.207 us; speedup 1.0000x reference)
//
#include <hip/hip_runtime.h>
#include <hip/hip_bf16.h>
#include <float.h>
#include <math.h>

typedef __hip_bfloat16 bf16;
typedef __attribute__((ext_vector_type(8))) short short8;
typedef __attribute__((ext_vector_type(4))) float f32x4;

__device__ __forceinline__ float bf2f(bf16 v){ return __bfloat162float(v); }
__device__ __forceinline__ void stv(float* p, float v){ *p = v; }
__device__ __forceinline__ void stv(bf16* p, float v){ *p = __float2bfloat16(v); }
__device__ __forceinline__ float nanfix(float v){
  if (v != v) return 0.f;
  return fminf(fmaxf(v, -FLT_MAX), FLT_MAX);
}
__device__ __forceinline__ unsigned short f2bu(float f){
  unsigned u = __float_as_uint(f);
  unsigned r = u + 0x7FFFu + ((u>>16)&1u);
  return (unsigned short)(r>>16);
}
template<int VEC>
__device__ __forceinline__ void ldbf(const bf16* p, float (&o)[VEC]){
  if constexpr (VEC==4){
    ushort4 r = *(const ushort4*)p;
    o[0]=__uint_as_float((unsigned)r.x<<16); o[1]=__uint_as_float((unsigned)r.y<<16);
    o[2]=__uint_as_float((unsigned)r.z<<16); o[3]=__uint_as_float((unsigned)r.w<<16);
  } else {
    ushort2 r = *(const ushort2*)p;
    o[0]=__uint_as_float((unsigned)r.x<<16); o[1]=__uint_as_float((unsigned)r.y<<16);
  }
}

// ---------------- edge degree + parallel scan + scatter ----------------
__global__ void k_deg(const int* __restrict__ tgt, int* __restrict__ deg, int E){
  int e = blockIdx.x*blockDim.x + threadIdx.x;
  if (e < E) atomicAdd(&deg[tgt[e]], 1);
}

__global__ void k_scan1(const int* __restrict__ deg, int* __restrict__ bsum, int N){
  __shared__ int sm[256];
  int i = blockIdx.x*256 + threadIdx.x;
  sm[threadIdx.x] = (i < N) ? deg[i] : 0;
  __syncthreads();
  for (int off = 128; off > 0; off >>= 1){
    if (threadIdx.x < off) sm[threadIdx.x] += sm[threadIdx.x + off];
    __syncthreads();
  }
  if (threadIdx.x == 0) bsum[blockIdx.x] = sm[0];
}

__global__ void k_scan2(int* __restrict__ bsum, int NB){
  __shared__ int sm[1024];
  int tid = threadIdx.x;
  sm[tid] = (tid < NB) ? bsum[tid] : 0;
  __syncthreads();
  for (int off = 1; off < 1024; off <<= 1){
    int t = (tid >= off) ? sm[tid-off] : 0;
    __syncthreads();
    sm[tid] += t;
    __syncthreads();
  }
  if (tid < NB) bsum[tid] = (tid == 0) ? 0 : sm[tid-1];   // exclusive block offsets
}

__global__ void k_scan3(const int* __restrict__ deg, const int* __restrict__ bsum,
                        int* __restrict__ offs, int N){
  __shared__ int sm[256];
  int tid = threadIdx.x;
  int i = blockIdx.x*256 + tid;
  int v = (i < N) ? deg[i] : 0;
  sm[tid] = v; __syncthreads();
  for (int off = 1; off < 256; off <<= 1){
    int t = (tid >= off) ? sm[tid-off] : 0;
    __syncthreads();
    sm[tid] += t;
    __syncthreads();
  }
  if (i < N) offs[i+1] = bsum[blockIdx.x] + sm[tid];
  if (i == 0) offs[0] = 0;
}

__global__ void k_scatter(const int* __restrict__ src, const int* __restrict__ tgt,
                          const int* __restrict__ offs, int* __restrict__ cnt,
                          int* __restrict__ ssrc, int E){
  int e = blockIdx.x*blockDim.x + threadIdx.x;
  if (e < E){
    int t = tgt[e];
    int pos = offs[t] + atomicAdd(&cnt[t], 1);
    ssrc[pos] = src[e];
  }
}

// ---------------- fused setup: weight repacks + x conversion (one dispatch) ----------------
__device__ __forceinline__ void rp_pqT(const float* preW, const float* preB,
                                       bf16* WpqT, float* bpq, int K, int F, int idx){
  int NC = 4*F;
  int total = 2*NC*K;
  if (idx < total){
    int j = idx/K, c = idx%K;
    int half = j/NC, jj = j%NC, t = jj/F, f = jj%F;
    WpqT[idx] = __float2bfloat16(preW[(t*2*K + half*K + c)*F + f]);
  }
  if (idx < 2*NC) bpq[idx] = (idx < NC) ? preB[idx] : 0.f;
}
__device__ __forceinline__ void rp_xT(const float* postW, const float* postB,
                                      bf16* WxT, float* bpost, int KX, int F, int idx){
  int NC = 4*F; int KP = KX + 12*F;
  if (idx < NC*KX){
    int j = idx/KX, c = idx%KX, t = j/F, f = j%F;
    WxT[idx] = __float2bfloat16(postW[(t*KP + c)*F + f]);
  }
  if (idx < NC) bpost[idx] = postB[idx];
}
__device__ __forceinline__ void rp_agg3(const float* postW, bf16* Wagg3,
                                        int KX, int F, int idx){
  int K4F = 4*F; int KP = KX + 12*F;
  int total = 4*3*F*K4F;
  if (idx < total){
    int k = idx % K4F; int r = idx / K4F;
    int zr = r % (3*F); int t = r / (3*F);
    int s = zr / F, f = zr % F;
    Wagg3[idx] = __float2bfloat16(postW[((size_t)(t*KP + KX + s*K4F + k))*F + f]);
  }
}
__device__ __forceinline__ void rp_linT(const float* linW, bf16* WlinT,
                                        int K, int NC, int idx){
  if (idx < NC*K){
    int j = idx/K, c = idx%K;
    WlinT[idx] = __float2bfloat16(linW[c*NC + j]);
  }
}

struct SetupArgs {
  const float *pre1W, *pre1b, *post1W, *post1b, *lin1W;
  const float *pre2W, *pre2b, *post2W, *post2b, *lin2W;
  const float *x;
  bf16 *WpqT1, *WxT1, *Wagg31, *lin1WT;
  bf16 *WpqT2, *WxT2, *Wagg32, *lin2WT;
  bf16 *x_bf;
  float *bpq1, *bpost1, *bpq2, *bpost2;
  int nx4;       // N*IN/4
  int gstride;   // gridDim.x*256
};

__global__ void k_setup(SetupArgs a){
  int idx = blockIdx.x*256 + threadIdx.x;
  switch (blockIdx.y){
    case 0: rp_pqT (a.pre1W, a.pre1b, a.WpqT1, a.bpq1, 128, 64, idx); break;
    case 1: rp_xT  (a.post1W, a.post1b, a.WxT1, a.bpost1, 128, 64, idx); break;
    case 2: rp_agg3(a.post1W, a.Wagg31, 128, 64, idx); break;
    case 3: rp_linT(a.lin1W, a.lin1WT, 256, 256, idx); break;
    case 4: rp_pqT (a.pre2W, a.pre2b, a.WpqT2, a.bpq2, 256, 32, idx); break;
    case 5: rp_xT  (a.post2W, a.post2b, a.WxT2, a.bpost2, 256, 32, idx); break;
    case 6: rp_agg3(a.post2W, a.Wagg32, 256, 32, idx); break;
    case 7: rp_linT(a.lin2W, a.lin2WT, 128, 128, idx); break;
    case 8:
      for (int i = idx; i < a.nx4; i += a.gstride){
        float4 v = *(const float4*)(a.x + (size_t)i*4);
        ushort4 o = make_ushort4(f2bu(v.x), f2bu(v.y), f2bu(v.z), f2bu(v.w));
        *(ushort4*)(a.x_bf + (size_t)i*4) = o;
      }
      break;
  }
}

// ---------------- MFMA GEMM: C[N, *] = A[N,K](bf16) @ Bt[NC,K]^T (bf16) ----------------
// 64x64 tile, 4 waves, each wave 32x32 via 2x2 mfma_f32_16x16x32_bf16.  (R8 proven config)
template<typename TO>
__global__ __launch_bounds__(256) void k_mgemm(
    const bf16* __restrict__ A, int lda,
    const bf16* __restrict__ Bt,
    const float* __restrict__ bias,
    TO* __restrict__ Cout, int ldc,
    int N, int K, int NC)
{
  __shared__ __align__(16) bf16 As[64*40];
  __shared__ __align__(16) bf16 Bs[64*40];
  int n0 = blockIdx.y*64;
  int j0 = blockIdx.x*64;
  int tid = threadIdx.x;
  int srow = tid>>2, skoff = (tid&3)*8;
  int wave = tid>>6, lane = tid&63;
  int wy = (wave>>1)*32, wx = (wave&1)*32;
  int l15 = lane&15, q = lane>>4;
  f32x4 acc[2][2] = {};
  for (int k0 = 0; k0 < K; k0 += 32){
    uint4 av = {0,0,0,0};
    int ar = n0 + srow;
    if (ar < N) av = *(const uint4*)(A + (size_t)ar*lda + k0 + skoff);
    *(uint4*)&As[srow*40 + skoff] = av;
    uint4 bv = {0,0,0,0};
    int br = j0 + srow;
    if (br < NC) bv = *(const uint4*)(Bt + (size_t)br*K + k0 + skoff);
    *(uint4*)&Bs[srow*40 + skoff] = bv;
    __syncthreads();
    short8 af[2], bfr[2];
    #pragma unroll
    for (int i = 0; i < 2; i++){
      af[i]  = *(const short8*)&As[(wy + i*16 + l15)*40 + q*8];
      bfr[i] = *(const short8*)&Bs[(wx + i*16 + l15)*40 + q*8];
    }
    #pragma unroll
    for (int mi = 0; mi < 2; mi++)
      #pragma unroll
      for (int ni = 0; ni < 2; ni++)
        acc[mi][ni] = __builtin_amdgcn_mfma_f32_16x16x32_bf16(af[mi], bfr[ni], acc[mi][ni], 0, 0, 0);
    __syncthreads();
  }
  #pragma unroll
  for (int mi = 0; mi < 2; mi++){
    #pragma unroll
    for (int ni = 0; ni < 2; ni++){
      #pragma unroll
      for (int r = 0; r < 4; r++){
        int n  = n0 + wy + mi*16 + q*4 + r;
        int jj = j0 + wx + ni*16 + l15;
        if (n < N && jj < NC){
          float v = acc[mi][ni][r] + bias[jj];
          stv(&Cout[(size_t)n*ldc + jj], v);
        }
      }
    }
  }
}

// ---------------- post-agg GEMM (phase-2 only): Cin (x@Wx+bias, bf16) read from PQX ----------------
// grid (1, NB, T). COLS = F per tower; K4F = 4*COLS; agg lda = 16*COLS (T=4 towers).
template<int COLS>
__global__ __launch_bounds__(256) void k_postagg(
    const bf16* __restrict__ agg,      // [N, 16*COLS]
    const bf16* __restrict__ Wagg3,    // [T][3*COLS][K4F]
    const bf16* __restrict__ PQX, int ldq, int cinOff,
    const float* __restrict__ scal,
    bf16* __restrict__ Cout, int ldc, int N)
{
  constexpr int K4F = 4*COLS;
  constexpr int ROWS3 = 3*COLS;
  constexpr int NI = COLS/32;          // 2 (COLS=64) or 1 (COLS=32)
  constexpr int LDA_AGG = 16*COLS;
  __shared__ __align__(16) bf16 As[64*40];
  __shared__ __align__(16) bf16 Bs[ROWS3*40];
  int z = blockIdx.z;
  int n0 = blockIdx.y*64;
  int tid = threadIdx.x;
  int srow = tid>>2, skoff = (tid&3)*8;
  int wave = tid>>6, lane = tid&63;
  int wy = (wave>>1)*32;
  int wx = (wave&1)*(COLS/2);
  int l15 = lane&15, q = lane>>4;
  f32x4 acc[2][NI][3] = {};
  const bf16* Az = agg + (size_t)z*K4F;
  const bf16* Bz = Wagg3 + (size_t)z*ROWS3*K4F;
  for (int k0 = 0; k0 < K4F; k0 += 32){
    uint4 av = {0,0,0,0};
    int ar = n0 + srow;
    if (ar < N) av = *(const uint4*)(Az + (size_t)ar*LDA_AGG + k0 + skoff);
    *(uint4*)&As[srow*40 + skoff] = av;
    for (int r = srow; r < ROWS3; r += 64){
      uint4 bv = *(const uint4*)(Bz + (size_t)r*K4F + k0 + skoff);
      *(uint4*)&Bs[r*40 + skoff] = bv;
    }
    __syncthreads();
    short8 af[2];
    #pragma unroll
    for (int i = 0; i < 2; i++)
      af[i] = *(const short8*)&As[(wy + i*16 + l15)*40 + q*8];
    #pragma unroll
    for (int s = 0; s < 3; s++){
      #pragma unroll
      for (int ni = 0; ni < NI; ni++){
        short8 bfr = *(const short8*)&Bs[(s*COLS + wx + ni*16 + l15)*40 + q*8];
        #pragma unroll
        for (int mi = 0; mi < 2; mi++)
          acc[mi][ni][s] = __builtin_amdgcn_mfma_f32_16x16x32_bf16(af[mi], bfr, acc[mi][ni][s], 0, 0, 0);
      }
    }
    __syncthreads();
  }
  #pragma unroll
  for (int mi = 0; mi < 2; mi++){
    #pragma unroll
    for (int ni = 0; ni < NI; ni++){
      int jj = wx + ni*16 + l15;
      int jg = z*COLS + jj;
      #pragma unroll
      for (int r = 0; r < 4; r++){
        int n = n0 + wy + mi*16 + q*4 + r;
        if (n < N){
          float s1 = scal[2*n], s2 = scal[2*n+1];
          float cin = bf2f(PQX[(size_t)n*ldq + cinOff + jg]);
          float v = cin + acc[mi][ni][0][r] + s1*acc[mi][ni][1][r] + s2*acc[mi][ni][2][r];
          Cout[(size_t)n*ldc + jg] = __float2bfloat16(v);
        }
      }
    }
  }
}

// ---------------- per-node PNA aggregation -> agg [N, T*4F] bf16 + scal ----------------
// node per wave; 8-edge unroll; stats computed on q and p-shifted at the end.
template<int NC, int F>
__global__ __launch_bounds__(256) void k_agg(const bf16* __restrict__ PQ, int lda,
    const int* __restrict__ ssrc, const int* __restrict__ offs,
    const float* __restrict__ avgp,
    bf16* __restrict__ agg, float* __restrict__ scal, int N){
  constexpr int VEC = NC/64;
  int wave = threadIdx.x>>6, lane = threadIdx.x&63;
  int n = blockIdx.x*4 + wave;
  if (n >= N) return;
  int c0 = lane*VEC;
  float p[VEC];
  ldbf<VEC>(PQ + (size_t)n*lda + c0, p);
  int s0 = offs[n], s1 = offs[n+1];
  float sum[VEC], sq[VEC], mn[VEC], mx[VEC];
  #pragma unroll
  for (int v=0;v<VEC;v++){ sum[v]=0.f; sq[v]=0.f; mn[v]=FLT_MAX; mx[v]=-FLT_MAX; }
  const bf16* Q = PQ + NC + c0;
  int i = s0;
  for (; i+7 < s1; i += 8){
    int se[8];
    #pragma unroll
    for (int u=0;u<8;u++) se[u] = ssrc[i+u];
    float qv[8][VEC];
    #pragma unroll
    for (int u=0;u<8;u++) ldbf<VEC>(Q + (size_t)se[u]*lda, qv[u]);
    #pragma unroll
    for (int u=0;u<8;u++){
      #pragma unroll
      for (int v=0;v<VEC;v++){
        float qq = qv[u][v];
        sum[v] += qq; sq[v] = fmaf(qq,qq,sq[v]);
        mn[v] = fminf(mn[v], qq); mx[v] = fmaxf(mx[v], qq);
      }
    }
  }
  for (; i+3 < s1; i += 4){
    int se[4];
    #pragma unroll
    for (int u=0;u<4;u++) se[u] = ssrc[i+u];
    float qv[4][VEC];
    #pragma unroll
    for (int u=0;u<4;u++) ldbf<VEC>(Q + (size_t)se[u]*lda, qv[u]);
    #pragma unroll
    for (int u=0;u<4;u++){
      #pragma unroll
      for (int v=0;v<VEC;v++){
        float qq = qv[u][v];
        sum[v] += qq; sq[v] = fmaf(qq,qq,sq[v]);
        mn[v] = fminf(mn[v], qq); mx[v] = fmaxf(mx[v], qq);
      }
    }
  }
  for (; i < s1; i++){
    int sa = ssrc[i];
    float qa[VEC];
    ldbf<VEC>(Q + (size_t)sa*lda, qa);
    #pragma unroll
    for (int v=0;v<VEC;v++){
      float qq = qa[v];
      sum[v]+=qq; sq[v]=fmaf(qq,qq,sq[v]); mn[v]=fminf(mn[v],qq); mx[v]=fmaxf(mx[v],qq);
    }
  }
  int deg = s1-s0;
  float degf = (float)deg;
  float degc = fmaxf(degf, 1.f);
  unsigned short um[VEC], un[VEC], ux[VEC], us[VEC];
  #pragma unroll
  for (int v=0;v<VEC;v++){
    float pv = p[v];
    float sum_m = fmaf(degf, pv, sum[v]);
    float sq_m  = sq[v] + 2.f*pv*sum[v] + degf*pv*pv;
    float mean = sum_m/degc;
    float var = fmaxf(sq_m/degc - mean*mean, 0.f);
    float sd = sqrtf(var + 1e-5f);
    float mnv = deg>0 ? pv + mn[v] : 0.f;
    float mxv = deg>0 ? pv + mx[v] : 0.f;
    um[v]=f2bu(mean); un[v]=f2bu(mnv); ux[v]=f2bu(mxv); us[v]=f2bu(sd);
  }
  int t = c0 / F, f0 = c0 % F;
  bf16* base = agg + (size_t)n*4*NC + (size_t)t*4*F + f0;
  if constexpr (VEC==4){
    *(ushort4*)(base)       = make_ushort4(um[0],um[1],um[2],um[3]);
    *(ushort4*)(base + F)   = make_ushort4(un[0],un[1],un[2],un[3]);
    *(ushort4*)(base + 2*F) = make_ushort4(ux[0],ux[1],ux[2],ux[3]);
    *(ushort4*)(base + 3*F) = make_ushort4(us[0],us[1],us[2],us[3]);
  } else {
    *(ushort2*)(base)       = make_ushort2(um[0],um[1]);
    *(ushort2*)(base + F)   = make_ushort2(un[0],un[1]);
    *(ushort2*)(base + 2*F) = make_ushort2(ux[0],ux[1]);
    *(ushort2*)(base + 3*F) = make_ushort2(us[0],us[1]);
  }
  if (lane==0){
    float dlog = logf(degc + 1.f);
    float avg = *avgp;
    scal[2*n]   = dlog/avg;
    scal[2*n+1] = avg/dlog;
  }
}

// ---------------- batch norm: two-phase, no hot atomics ----------------
template<int C>
__global__ __launch_bounds__(256) void k_bn_part(const float* __restrict__ h,
                                                 float* __restrict__ part, int N){
  constexpr int C4 = C/4;
  constexpr int RG = 256/C4;
  constexpr int RPB = 128;
  int c4 = threadIdx.x % C4, rg = threadIdx.x / C4;
  int n0 = blockIdx.x*RPB;
  int n1 = min(n0 + RPB, N);
  float4 s = {0,0,0,0}, q = {0,0,0,0};
  for (int n = n0 + rg; n < n1; n += RG){
    float4 v = *(const float4*)(h + (size_t)n*C + c4*4);
    v.x = nanfix(v.x); v.y = nanfix(v.y); v.z = nanfix(v.z); v.w = nanfix(v.w);
    s.x += v.x; s.y += v.y; s.z += v.z; s.w += v.w;
    q.x += v.x*v.x; q.y += v.y*v.y; q.z += v.z*v.z; q.w += v.w*v.w;
  }
  __shared__ float4 ssum[256], ssq[256];
  ssum[threadIdx.x] = s; ssq[threadIdx.x] = q;
  __syncthreads();
  if (rg == 0){
    #pragma unroll
    for (int g = 1; g < RG; g++){
      float4 o = ssum[g*C4 + c4];
      s.x += o.x; s.y += o.y; s.z += o.z; s.w += o.w;
      float4 p = ssq[g*C4 + c4];
      q.x += p.x; q.y += p.y; q.z += p.z; q.w += p.w;
    }
    float* dst = part + (size_t)blockIdx.x*2*C;
    *(float4*)(dst + c4*4)     = s;
    *(float4*)(dst + C + c4*4) = q;
  }
}

template<int C>
__global__ __launch_bounds__(256) void k_bn_final(const float* __restrict__ part, int PB,
                                                  float* __restrict__ stats){
  int c = blockIdx.x*256 + threadIdx.x;
  if (c >= 2*C) return;
  int CH = gridDim.y;
  int per = (PB + CH - 1)/CH;
  int p0 = blockIdx.y*per, p1 = min(p0 + per, PB);
  float acc = 0.f;
  int p = p0;
  for (; p+4 <= p1; p += 4){
    acc += part[(size_t)p*2*C + c] + part[(size_t)(p+1)*2*C + c]
         + part[(size_t)(p+2)*2*C + c] + part[(size_t)(p+3)*2*C + c];
  }
  for (; p < p1; p++) acc += part[(size_t)p*2*C + c];
  atomicAdd(&stats[c], acc);
}

template<typename TO, int C>
__global__ void k_bn_apply(const float* __restrict__ h, const float* __restrict__ stats,
     const float* __restrict__ g, const float* __restrict__ b,
     TO* __restrict__ out, int N){
  int idx = blockIdx.x*blockDim.x + threadIdx.x;   // quad index
  if (idx >= N*(C/4)) return;
  int c = (idx % (C/4))*4;
  float fn = (float)N;
  float4 v = *(const float4*)(h + (size_t)idx*4);
  float r[4];
  #pragma unroll
  for (int k = 0; k < 4; k++){
    float m = stats[c+k]/fn;
    float var = fmaxf(stats[C+c+k]/fn - m*m, 0.f);
    float inv = rsqrtf(var + 1e-5f);
    float vv = nanfix(((const float*)&v)[k]);
    r[k] = fmaxf(g[c+k]*(vv - m)*inv + b[c+k], 0.f);
  }
  if constexpr (sizeof(TO) == 4){
    float4 o = {r[0], r[1], r[2], r[3]};
    *(float4*)((float*)out + (size_t)idx*4) = o;
  } else {
    ushort4 o = make_ushort4(f2bu(r[0]), f2bu(r[1]), f2bu(r[2]), f2bu(r[3]));
    *(ushort4*)((bf16*)out + (size_t)idx*4) = o;
  }
}

static inline int cdiv(int a, int b){ return (a + b - 1)/b; }

extern "C" void kernel_launch(void* const* d_in, const int* in_sizes, int n_in,
                              void* d_out, int out_size, void* d_ws, size_t ws_size,
                              hipStream_t stream){
  const int IN = 128, HID = 256, T = 4, F1 = 64, F2 = 32;
  const int N = in_sizes[0]/IN;
  const int E = in_sizes[1]/2;
  const int NC1 = T*F1;        // 256
  const int NC2 = T*F2;        // 128
  const int LDQ1 = 2*NC1 + NC1;   // 768: [P|Q|postX]
  const int LDQ2 = 2*NC2 + NC2;   // 384

  const float* x      = (const float*)d_in[0];
  const int*   ei     = (const int*)  d_in[1];
  const int*   srcE   = ei;
  const int*   tgtE   = ei + E;
  const float* avgp   = (const float*)d_in[2];
  const float* pre1W  = (const float*)d_in[3];
  const float* pre1b  = (const float*)d_in[4];
  const float* post1W = (const float*)d_in[5];
  const float* post1b = (const float*)d_in[6];
  const float* lin1W  = (const float*)d_in[7];
  const float* lin1b  = (const float*)d_in[8];
  const float* bn1g   = (const float*)d_in[9];
  const float* bn1b   = (const float*)d_in[10];
  const float* pre2W  = (const float*)d_in[11];
  const float* pre2b  = (const float*)d_in[12];
  const float* post2W = (const float*)d_in[13];
  const float* post2b = (const float*)d_in[14];
  const float* lin2W  = (const float*)d_in[15];
  const float* lin2b  = (const float*)d_in[16];
  const float* bn2g   = (const float*)d_in[17];
  const float* bn2b   = (const float*)d_in[18];

  // ---- workspace carve ----
  char* w = (char*)d_ws;
  auto alloc = [&](size_t bytes)->void*{
    void* p = (void*)w; w += (bytes + 255) & ~(size_t)255; return p;
  };
  // combined B^T for pre-GEMM: [WpqT (2*NC rows) | WxT (NC rows)], contiguous
  bf16* BT1    = (bf16*)alloc((size_t)LDQ1*IN*2);
  bf16* WpqT1  = BT1;              bf16* WxT1 = BT1 + (size_t)2*NC1*IN;
  float* bias1 = (float*)alloc((size_t)LDQ1*4);
  float* bpq1  = bias1;            float* bpost1 = bias1 + 2*NC1;
  bf16* Wagg31 = (bf16*)alloc((size_t)T*3*F1*4*F1*2);
  bf16* lin1WT = (bf16*)alloc((size_t)HID*NC1*2);
  bf16* BT2    = (bf16*)alloc((size_t)LDQ2*HID*2);
  bf16* WpqT2  = BT2;              bf16* WxT2 = BT2 + (size_t)2*NC2*HID;
  float* bias2 = (float*)alloc((size_t)LDQ2*4);
  float* bpq2  = bias2;            float* bpost2 = bias2 + 2*NC2;
  bf16* Wagg32 = (bf16*)alloc((size_t)T*3*F2*4*F2*2);
  bf16* lin2WT = (bf16*)alloc((size_t)128*NC2*2);
  // zero region: deg_i | cnt | stats (one memset)
  int* deg_i   = (int*)alloc((size_t)N*4);
  int* cnt     = (int*)alloc((size_t)N*4);
  float* stats = (float*)alloc(1024*4);
  size_t zbytes = (size_t)((char*)stats - (char*)deg_i) + 1024*4;
  int* offs    = (int*)alloc((size_t)(N+1)*4);
  int* bsum    = (int*)alloc((size_t)cdiv(N,256)*4);
  int* ssrc    = (int*)alloc((size_t)E*4);
  bf16* x_bf   = (bf16*)alloc((size_t)N*IN*2);
  bf16* PQX    = (bf16*)alloc((size_t)N*LDQ1*2);   // L2 reuses prefix [N, LDQ2]
  bf16* aggb   = (bf16*)alloc((size_t)N*4*NC1*2);  // L2 reuses prefix [N, 4*NC2]
  float* scal  = (float*)alloc((size_t)N*2*4);
  bf16* postbb = (bf16*)alloc((size_t)N*256*2);
  float* hpre  = (float*)alloc((size_t)N*256*4);
  bf16* h1b    = (bf16*)alloc((size_t)N*256*2);
  int PB = cdiv(N,128);
  float* part  = (float*)alloc((size_t)PB*512*4);

  hipMemsetAsync(deg_i, 0, zbytes, stream);

  // ---- setup: all weight repacks + x conversion (one dispatch) ----
  int sgx = cdiv(T*3*F1*4*F1, 256);   // 768 blocks covers the largest segment
  SetupArgs sa = { pre1W, pre1b, post1W, post1b, lin1W,
                   pre2W, pre2b, post2W, post2b, lin2W,
                   x,
                   WpqT1, WxT1, Wagg31, lin1WT,
                   WpqT2, WxT2, Wagg32, lin2WT,
                   x_bf,
                   bpq1, bpost1, bpq2, bpost2,
                   N*IN/4, sgx*256 };
  k_setup<<<dim3(sgx, 9),256,0,stream>>>(sa);

  // ---- counting sort of edges by target (parallel scan) ----
  int NBs = cdiv(N,256);
  k_deg<<<cdiv(E,256),256,0,stream>>>(tgtE, deg_i, E);
  k_scan1<<<NBs,256,0,stream>>>(deg_i, bsum, N);
  k_scan2<<<1,1024,0,stream>>>(bsum, NBs);
  k_scan3<<<NBs,256,0,stream>>>(deg_i, bsum, offs, N);
  k_scatter<<<cdiv(E,256),256,0,stream>>>(srcE, tgtE, offs, cnt, ssrc, E);

  int NB = cdiv(N,64);

  // ================= Layer 1 =================
  k_mgemm<bf16><<<dim3(LDQ1/64,NB),256,0,stream>>>(x_bf, IN, BT1, bias1, PQX, LDQ1, N, IN, LDQ1);
  k_agg<256,64><<<cdiv(N,4),256,0,stream>>>(PQX, LDQ1, ssrc, offs, avgp, aggb, scal, N);
  k_postagg<64><<<dim3(1,NB,T),256,0,stream>>>(aggb, Wagg31, PQX, LDQ1, 2*NC1, scal,
                                               postbb, NC1, N);
  k_mgemm<float><<<dim3(4,NB),256,0,stream>>>(postbb, NC1, lin1WT, lin1b, hpre, HID, N, NC1, HID);
  k_bn_part<256><<<PB,256,0,stream>>>(hpre, part, N);
  k_bn_final<256><<<dim3(2,4),256,0,stream>>>(part, PB, stats);
  k_bn_apply<bf16,256><<<cdiv(N*64,256),256,0,stream>>>(hpre, stats, bn1g, bn1b, h1b, N);

  // ================= Layer 2 =================
  k_mgemm<bf16><<<dim3(LDQ2/64,NB),256,0,stream>>>(h1b, HID, BT2, bias2, PQX, LDQ2, N, HID, LDQ2);
  k_agg<128,32><<<cdiv(N,4),256,0,stream>>>(PQX, LDQ2, ssrc, offs, avgp, aggb, scal, N);
  k_postagg<32><<<dim3(1,NB,T),256,0,stream>>>(aggb, Wagg32, PQX, LDQ2, 2*NC2, scal,
                                               postbb, NC2, N);
  k_mgemm<float><<<dim3(2,NB),256,0,stream>>>(postbb, NC2, lin2WT, lin2b, hpre, 128, N, NC2, 128);
  k_bn_part<128><<<PB,256,0,stream>>>(hpre, part, N);
  k_bn_final<128><<<dim3(1,4),256,0,stream>>>(part, PB, stats + 512);
  k_bn_apply<float,128><<<cdiv(N*32,256),256,0,stream>>>(hpre, stats + 512, bn2g, bn2b, (float*)d_out, N);
}

// Round 15
// 381.944 us; speedup vs baseline: 1.0085x; 1.0085x over previous
//
#include <hip/hip_runtime.h>
#include <hip/hip_bf16.h>
#include <float.h>
#include <math.h>

typedef __hip_bfloat16 bf16;
typedef __attribute__((ext_vector_type(8))) short short8;
typedef __attribute__((ext_vector_type(4))) float f32x4;

__device__ __forceinline__ float bf2f(bf16 v){ return __bfloat162float(v); }
__device__ __forceinline__ void stv(float* p, float v){ *p = v; }
__device__ __forceinline__ void stv(bf16* p, float v){ *p = __float2bfloat16(v); }
__device__ __forceinline__ float nanfix(float v){
  if (v != v) return 0.f;
  return fminf(fmaxf(v, -FLT_MAX), FLT_MAX);
}
__device__ __forceinline__ unsigned short f2bu(float f){
  unsigned u = __float_as_uint(f);
  unsigned r = u + 0x7FFFu + ((u>>16)&1u);
  return (unsigned short)(r>>16);
}
template<int VEC>
__device__ __forceinline__ void ldbf(const bf16* p, float (&o)[VEC]){
  if constexpr (VEC==4){
    ushort4 r = *(const ushort4*)p;
    o[0]=__uint_as_float((unsigned)r.x<<16); o[1]=__uint_as_float((unsigned)r.y<<16);
    o[2]=__uint_as_float((unsigned)r.z<<16); o[3]=__uint_as_float((unsigned)r.w<<16);
  } else {
    ushort2 r = *(const ushort2*)p;
    o[0]=__uint_as_float((unsigned)r.x<<16); o[1]=__uint_as_float((unsigned)r.y<<16);
  }
}

// ---------------- parallel scan + scatter (deg lives in k_setup) ----------------
__global__ void k_scan1(const int* __restrict__ deg, int* __restrict__ bsum, int N){
  __shared__ int sm[256];
  int i = blockIdx.x*256 + threadIdx.x;
  sm[threadIdx.x] = (i < N) ? deg[i] : 0;
  __syncthreads();
  for (int off = 128; off > 0; off >>= 1){
    if (threadIdx.x < off) sm[threadIdx.x] += sm[threadIdx.x + off];
    __syncthreads();
  }
  if (threadIdx.x == 0) bsum[blockIdx.x] = sm[0];
}

__global__ void k_scan2(int* __restrict__ bsum, int NB){
  __shared__ int sm[1024];
  int tid = threadIdx.x;
  sm[tid] = (tid < NB) ? bsum[tid] : 0;
  __syncthreads();
  for (int off = 1; off < 1024; off <<= 1){
    int t = (tid >= off) ? sm[tid-off] : 0;
    __syncthreads();
    sm[tid] += t;
    __syncthreads();
  }
  if (tid < NB) bsum[tid] = (tid == 0) ? 0 : sm[tid-1];   // exclusive block offsets
}

__global__ void k_scan3(const int* __restrict__ deg, const int* __restrict__ bsum,
                        int* __restrict__ offs, int N){
  __shared__ int sm[256];
  int tid = threadIdx.x;
  int i = blockIdx.x*256 + tid;
  int v = (i < N) ? deg[i] : 0;
  sm[tid] = v; __syncthreads();
  for (int off = 1; off < 256; off <<= 1){
    int t = (tid >= off) ? sm[tid-off] : 0;
    __syncthreads();
    sm[tid] += t;
    __syncthreads();
  }
  if (i < N) offs[i+1] = bsum[blockIdx.x] + sm[tid];
  if (i == 0) offs[0] = 0;
}

__global__ void k_scatter(const int* __restrict__ src, const int* __restrict__ tgt,
                          const int* __restrict__ offs, int* __restrict__ cnt,
                          int* __restrict__ ssrc, int E){
  int e = blockIdx.x*blockDim.x + threadIdx.x;
  if (e < E){
    int t = tgt[e];
    int pos = offs[t] + atomicAdd(&cnt[t], 1);
    ssrc[pos] = src[e];
  }
}

// ---------------- fused setup: weight repacks + x conversion + degree count ----------------
__device__ __forceinline__ void rp_pqT(const float* preW, const float* preB,
                                       bf16* WpqT, float* bpq, int K, int F, int idx){
  int NC = 4*F;
  int total = 2*NC*K;
  if (idx < total){
    int j = idx/K, c = idx%K;
    int half = j/NC, jj = j%NC, t = jj/F, f = jj%F;
    WpqT[idx] = __float2bfloat16(preW[(t*2*K + half*K + c)*F + f]);
  }
  if (idx < 2*NC) bpq[idx] = (idx < NC) ? preB[idx] : 0.f;
}
__device__ __forceinline__ void rp_xT(const float* postW, const float* postB,
                                      bf16* WxT, float* bpost, int KX, int F, int idx){
  int NC = 4*F; int KP = KX + 12*F;
  if (idx < NC*KX){
    int j = idx/KX, c = idx%KX, t = j/F, f = j%F;
    WxT[idx] = __float2bfloat16(postW[(t*KP + c)*F + f]);
  }
  if (idx < NC) bpost[idx] = postB[idx];
}
__device__ __forceinline__ void rp_agg3(const float* postW, bf16* Wagg3,
                                        int KX, int F, int idx){
  int K4F = 4*F; int KP = KX + 12*F;
  int total = 4*3*F*K4F;
  if (idx < total){
    int k = idx % K4F; int r = idx / K4F;
    int zr = r % (3*F); int t = r / (3*F);
    int s = zr / F, f = zr % F;
    Wagg3[idx] = __float2bfloat16(postW[((size_t)(t*KP + KX + s*K4F + k))*F + f]);
  }
}
__device__ __forceinline__ void rp_linT(const float* linW, bf16* WlinT,
                                        int K, int NC, int idx){
  if (idx < NC*K){
    int j = idx/K, c = idx%K;
    WlinT[idx] = __float2bfloat16(linW[c*NC + j]);
  }
}

struct SetupArgs {
  const float *pre1W, *pre1b, *post1W, *post1b, *lin1W;
  const float *pre2W, *pre2b, *post2W, *post2b, *lin2W;
  const float *x;
  const int *tgt;
  bf16 *WpqT1, *WxT1, *Wagg31, *lin1WT;
  bf16 *WpqT2, *WxT2, *Wagg32, *lin2WT;
  bf16 *x_bf;
  int *deg;
  float *bpq1, *bpost1, *bpq2, *bpost2;
  int nx4;       // N*IN/4
  int E;
  int gstride;   // gridDim.x*256
};

__global__ void k_setup(SetupArgs a){
  int idx = blockIdx.x*256 + threadIdx.x;
  switch (blockIdx.y){
    case 0: rp_pqT (a.pre1W, a.pre1b, a.WpqT1, a.bpq1, 128, 64, idx); break;
    case 1: rp_xT  (a.post1W, a.post1b, a.WxT1, a.bpost1, 128, 64, idx); break;
    case 2: rp_agg3(a.post1W, a.Wagg31, 128, 64, idx); break;
    case 3: rp_linT(a.lin1W, a.lin1WT, 256, 256, idx); break;
    case 4: rp_pqT (a.pre2W, a.pre2b, a.WpqT2, a.bpq2, 256, 32, idx); break;
    case 5: rp_xT  (a.post2W, a.post2b, a.WxT2, a.bpost2, 256, 32, idx); break;
    case 6: rp_agg3(a.post2W, a.Wagg32, 256, 32, idx); break;
    case 7: rp_linT(a.lin2W, a.lin2WT, 128, 128, idx); break;
    case 8:
      for (int i = idx; i < a.nx4; i += a.gstride){
        float4 v = *(const float4*)(a.x + (size_t)i*4);
        ushort4 o = make_ushort4(f2bu(v.x), f2bu(v.y), f2bu(v.z), f2bu(v.w));
        *(ushort4*)(a.x_bf + (size_t)i*4) = o;
      }
      break;
    case 9:
      for (int e = idx; e < a.E; e += a.gstride)
        atomicAdd(&a.deg[a.tgt[e]], 1);
      break;
  }
}

// ---------------- MFMA GEMM: C[N, *] = A[N,K](bf16) @ Bt[NC,K]^T (bf16) ----------------
// 64x64 tile, 4 waves, each wave 32x32 via 2x2 mfma_f32_16x16x32_bf16.  (R8 proven config)
template<typename TO>
__global__ __launch_bounds__(256) void k_mgemm(
    const bf16* __restrict__ A, int lda,
    const bf16* __restrict__ Bt,
    const float* __restrict__ bias,
    TO* __restrict__ Cout, int ldc,
    int N, int K, int NC)
{
  __shared__ __align__(16) bf16 As[64*40];
  __shared__ __align__(16) bf16 Bs[64*40];
  int n0 = blockIdx.y*64;
  int j0 = blockIdx.x*64;
  int tid = threadIdx.x;
  int srow = tid>>2, skoff = (tid&3)*8;
  int wave = tid>>6, lane = tid&63;
  int wy = (wave>>1)*32, wx = (wave&1)*32;
  int l15 = lane&15, q = lane>>4;
  f32x4 acc[2][2] = {};
  for (int k0 = 0; k0 < K; k0 += 32){
    uint4 av = {0,0,0,0};
    int ar = n0 + srow;
    if (ar < N) av = *(const uint4*)(A + (size_t)ar*lda + k0 + skoff);
    *(uint4*)&As[srow*40 + skoff] = av;
    uint4 bv = {0,0,0,0};
    int br = j0 + srow;
    if (br < NC) bv = *(const uint4*)(Bt + (size_t)br*K + k0 + skoff);
    *(uint4*)&Bs[srow*40 + skoff] = bv;
    __syncthreads();
    short8 af[2], bfr[2];
    #pragma unroll
    for (int i = 0; i < 2; i++){
      af[i]  = *(const short8*)&As[(wy + i*16 + l15)*40 + q*8];
      bfr[i] = *(const short8*)&Bs[(wx + i*16 + l15)*40 + q*8];
    }
    #pragma unroll
    for (int mi = 0; mi < 2; mi++)
      #pragma unroll
      for (int ni = 0; ni < 2; ni++)
        acc[mi][ni] = __builtin_amdgcn_mfma_f32_16x16x32_bf16(af[mi], bfr[ni], acc[mi][ni], 0, 0, 0);
    __syncthreads();
  }
  #pragma unroll
  for (int mi = 0; mi < 2; mi++){
    #pragma unroll
    for (int ni = 0; ni < 2; ni++){
      #pragma unroll
      for (int r = 0; r < 4; r++){
        int n  = n0 + wy + mi*16 + q*4 + r;
        int jj = j0 + wx + ni*16 + l15;
        if (n < N && jj < NC){
          float v = acc[mi][ni][r] + bias[jj];
          stv(&Cout[(size_t)n*ldc + jj], v);
        }
      }
    }
  }
}

// ---------------- post-agg GEMM (phase-2 only): Cin (x@Wx+bias, bf16) read from PQX ----------------
template<int COLS>
__global__ __launch_bounds__(256) void k_postagg(
    const bf16* __restrict__ agg,      // [N, 16*COLS]
    const bf16* __restrict__ Wagg3,    // [T][3*COLS][K4F]
    const bf16* __restrict__ PQX, int ldq, int cinOff,
    const float* __restrict__ scal,
    bf16* __restrict__ Cout, int ldc, int N)
{
  constexpr int K4F = 4*COLS;
  constexpr int ROWS3 = 3*COLS;
  constexpr int NI = COLS/32;          // 2 (COLS=64) or 1 (COLS=32)
  constexpr int LDA_AGG = 16*COLS;
  __shared__ __align__(16) bf16 As[64*40];
  __shared__ __align__(16) bf16 Bs[ROWS3*40];
  int z = blockIdx.z;
  int n0 = blockIdx.y*64;
  int tid = threadIdx.x;
  int srow = tid>>2, skoff = (tid&3)*8;
  int wave = tid>>6, lane = tid&63;
  int wy = (wave>>1)*32;
  int wx = (wave&1)*(COLS/2);
  int l15 = lane&15, q = lane>>4;
  f32x4 acc[2][NI][3] = {};
  const bf16* Az = agg + (size_t)z*K4F;
  const bf16* Bz = Wagg3 + (size_t)z*ROWS3*K4F;
  for (int k0 = 0; k0 < K4F; k0 += 32){
    uint4 av = {0,0,0,0};
    int ar = n0 + srow;
    if (ar < N) av = *(const uint4*)(Az + (size_t)ar*LDA_AGG + k0 + skoff);
    *(uint4*)&As[srow*40 + skoff] = av;
    for (int r = srow; r < ROWS3; r += 64){
      uint4 bv = *(const uint4*)(Bz + (size_t)r*K4F + k0 + skoff);
      *(uint4*)&Bs[r*40 + skoff] = bv;
    }
    __syncthreads();
    short8 af[2];
    #pragma unroll
    for (int i = 0; i < 2; i++)
      af[i] = *(const short8*)&As[(wy + i*16 + l15)*40 + q*8];
    #pragma unroll
    for (int s = 0; s < 3; s++){
      #pragma unroll
      for (int ni = 0; ni < NI; ni++){
        short8 bfr = *(const short8*)&Bs[(s*COLS + wx + ni*16 + l15)*40 + q*8];
        #pragma unroll
        for (int mi = 0; mi < 2; mi++)
          acc[mi][ni][s] = __builtin_amdgcn_mfma_f32_16x16x32_bf16(af[mi], bfr, acc[mi][ni][s], 0, 0, 0);
      }
    }
    __syncthreads();
  }
  #pragma unroll
  for (int mi = 0; mi < 2; mi++){
    #pragma unroll
    for (int ni = 0; ni < NI; ni++){
      int jj = wx + ni*16 + l15;
      int jg = z*COLS + jj;
      #pragma unroll
      for (int r = 0; r < 4; r++){
        int n = n0 + wy + mi*16 + q*4 + r;
        if (n < N){
          float s1 = scal[2*n], s2 = scal[2*n+1];
          float cin = bf2f(PQX[(size_t)n*ldq + cinOff + jg]);
          float v = cin + acc[mi][ni][0][r] + s1*acc[mi][ni][1][r] + s2*acc[mi][ni][2][r];
          Cout[(size_t)n*ldc + jg] = __float2bfloat16(v);
        }
      }
    }
  }
}

// ---------------- per-node PNA aggregation -> agg [N, T*4F] bf16 + scal ----------------
// node per wave; 8-edge unroll; stats computed on q and p-shifted at the end.
template<int NC, int F>
__global__ __launch_bounds__(256) void k_agg(const bf16* __restrict__ PQ, int lda,
    const int* __restrict__ ssrc, const int* __restrict__ offs,
    const float* __restrict__ avgp,
    bf16* __restrict__ agg, float* __restrict__ scal, int N){
  constexpr int VEC = NC/64;
  int wave = threadIdx.x>>6, lane = threadIdx.x&63;
  int n = blockIdx.x*4 + wave;
  if (n >= N) return;
  int c0 = lane*VEC;
  float p[VEC];
  ldbf<VEC>(PQ + (size_t)n*lda + c0, p);
  int s0 = offs[n], s1 = offs[n+1];
  float sum[VEC], sq[VEC], mn[VEC], mx[VEC];
  #pragma unroll
  for (int v=0;v<VEC;v++){ sum[v]=0.f; sq[v]=0.f; mn[v]=FLT_MAX; mx[v]=-FLT_MAX; }
  const bf16* Q = PQ + NC + c0;
  int i = s0;
  for (; i+7 < s1; i += 8){
    int se[8];
    #pragma unroll
    for (int u=0;u<8;u++) se[u] = ssrc[i+u];
    float qv[8][VEC];
    #pragma unroll
    for (int u=0;u<8;u++) ldbf<VEC>(Q + (size_t)se[u]*lda, qv[u]);
    #pragma unroll
    for (int u=0;u<8;u++){
      #pragma unroll
      for (int v=0;v<VEC;v++){
        float qq = qv[u][v];
        sum[v] += qq; sq[v] = fmaf(qq,qq,sq[v]);
        mn[v] = fminf(mn[v], qq); mx[v] = fmaxf(mx[v], qq);
      }
    }
  }
  for (; i+3 < s1; i += 4){
    int se[4];
    #pragma unroll
    for (int u=0;u<4;u++) se[u] = ssrc[i+u];
    float qv[4][VEC];
    #pragma unroll
    for (int u=0;u<4;u++) ldbf<VEC>(Q + (size_t)se[u]*lda, qv[u]);
    #pragma unroll
    for (int u=0;u<4;u++){
      #pragma unroll
      for (int v=0;v<VEC;v++){
        float qq = qv[u][v];
        sum[v] += qq; sq[v] = fmaf(qq,qq,sq[v]);
        mn[v] = fminf(mn[v], qq); mx[v] = fmaxf(mx[v], qq);
      }
    }
  }
  for (; i < s1; i++){
    int sa = ssrc[i];
    float qa[VEC];
    ldbf<VEC>(Q + (size_t)sa*lda, qa);
    #pragma unroll
    for (int v=0;v<VEC;v++){
      float qq = qa[v];
      sum[v]+=qq; sq[v]=fmaf(qq,qq,sq[v]); mn[v]=fminf(mn[v],qq); mx[v]=fmaxf(mx[v],qq);
    }
  }
  int deg = s1-s0;
  float degf = (float)deg;
  float degc = fmaxf(degf, 1.f);
  unsigned short um[VEC], un[VEC], ux[VEC], us[VEC];
  #pragma unroll
  for (int v=0;v<VEC;v++){
    float pv = p[v];
    float sum_m = fmaf(degf, pv, sum[v]);
    float sq_m  = sq[v] + 2.f*pv*sum[v] + degf*pv*pv;
    float mean = sum_m/degc;
    float var = fmaxf(sq_m/degc - mean*mean, 0.f);
    float sd = sqrtf(var + 1e-5f);
    float mnv = deg>0 ? pv + mn[v] : 0.f;
    float mxv = deg>0 ? pv + mx[v] : 0.f;
    um[v]=f2bu(mean); un[v]=f2bu(mnv); ux[v]=f2bu(mxv); us[v]=f2bu(sd);
  }
  int t = c0 / F, f0 = c0 % F;
  bf16* base = agg + (size_t)n*4*NC + (size_t)t*4*F + f0;
  if constexpr (VEC==4){
    *(ushort4*)(base)       = make_ushort4(um[0],um[1],um[2],um[3]);
    *(ushort4*)(base + F)   = make_ushort4(un[0],un[1],un[2],un[3]);
    *(ushort4*)(base + 2*F) = make_ushort4(ux[0],ux[1],ux[2],ux[3]);
    *(ushort4*)(base + 3*F) = make_ushort4(us[0],us[1],us[2],us[3]);
  } else {
    *(ushort2*)(base)       = make_ushort2(um[0],um[1]);
    *(ushort2*)(base + F)   = make_ushort2(un[0],un[1]);
    *(ushort2*)(base + 2*F) = make_ushort2(ux[0],ux[1]);
    *(ushort2*)(base + 3*F) = make_ushort2(us[0],us[1]);
  }
  if (lane==0){
    float dlog = logf(degc + 1.f);
    float avg = *avgp;
    scal[2*n]   = dlog/avg;
    scal[2*n+1] = avg/dlog;
  }
}

// ---------------- batch norm: two-phase, bf16 input ----------------
template<int C>
__global__ __launch_bounds__(256) void k_bn_part(const bf16* __restrict__ h,
                                                 float* __restrict__ part, int N){
  constexpr int C4 = C/4;
  constexpr int RG = 256/C4;
  constexpr int RPB = 128;
  int c4 = threadIdx.x % C4, rg = threadIdx.x / C4;
  int n0 = blockIdx.x*RPB;
  int n1 = min(n0 + RPB, N);
  float4 s = {0,0,0,0}, q = {0,0,0,0};
  for (int n = n0 + rg; n < n1; n += RG){
    float v[4];
    ldbf<4>(h + (size_t)n*C + c4*4, v);
    #pragma unroll
    for (int k=0;k<4;k++) v[k] = nanfix(v[k]);
    s.x += v[0]; s.y += v[1]; s.z += v[2]; s.w += v[3];
    q.x += v[0]*v[0]; q.y += v[1]*v[1]; q.z += v[2]*v[2]; q.w += v[3]*v[3];
  }
  __shared__ float4 ssum[256], ssq[256];
  ssum[threadIdx.x] = s; ssq[threadIdx.x] = q;
  __syncthreads();
  if (rg == 0){
    #pragma unroll
    for (int g = 1; g < RG; g++){
      float4 o = ssum[g*C4 + c4];
      s.x += o.x; s.y += o.y; s.z += o.z; s.w += o.w;
      float4 p = ssq[g*C4 + c4];
      q.x += p.x; q.y += p.y; q.z += p.z; q.w += p.w;
    }
    float* dst = part + (size_t)blockIdx.x*2*C;
    *(float4*)(dst + c4*4)     = s;
    *(float4*)(dst + C + c4*4) = q;
  }
}

template<int C>
__global__ __launch_bounds__(256) void k_bn_final(const float* __restrict__ part, int PB,
                                                  float* __restrict__ stats){
  int c = blockIdx.x*256 + threadIdx.x;
  if (c >= 2*C) return;
  int CH = gridDim.y;
  int per = (PB + CH - 1)/CH;
  int p0 = blockIdx.y*per, p1 = min(p0 + per, PB);
  float acc = 0.f;
  int p = p0;
  for (; p+4 <= p1; p += 4){
    acc += part[(size_t)p*2*C + c] + part[(size_t)(p+1)*2*C + c]
         + part[(size_t)(p+2)*2*C + c] + part[(size_t)(p+3)*2*C + c];
  }
  for (; p < p1; p++) acc += part[(size_t)p*2*C + c];
  atomicAdd(&stats[c], acc);
}

template<typename TO, int C>
__global__ void k_bn_apply(const bf16* __restrict__ h, const float* __restrict__ stats,
     const float* __restrict__ g, const float* __restrict__ b,
     TO* __restrict__ out, int N){
  int idx = blockIdx.x*blockDim.x + threadIdx.x;   // quad index
  if (idx >= N*(C/4)) return;
  int c = (idx % (C/4))*4;
  float fn = (float)N;
  float v[4];
  ldbf<4>(h + (size_t)idx*4, v);
  float r[4];
  #pragma unroll
  for (int k = 0; k < 4; k++){
    float m = stats[c+k]/fn;
    float var = fmaxf(stats[C+c+k]/fn - m*m, 0.f);
    float inv = rsqrtf(var + 1e-5f);
    float vv = nanfix(v[k]);
    r[k] = fmaxf(g[c+k]*(vv - m)*inv + b[c+k], 0.f);
  }
  if constexpr (sizeof(TO) == 4){
    float4 o = {r[0], r[1], r[2], r[3]};
    *(float4*)((float*)out + (size_t)idx*4) = o;
  } else {
    ushort4 o = make_ushort4(f2bu(r[0]), f2bu(r[1]), f2bu(r[2]), f2bu(r[3]));
    *(ushort4*)((bf16*)out + (size_t)idx*4) = o;
  }
}

static inline int cdiv(int a, int b){ return (a + b - 1)/b; }

extern "C" void kernel_launch(void* const* d_in, const int* in_sizes, int n_in,
                              void* d_out, int out_size, void* d_ws, size_t ws_size,
                              hipStream_t stream){
  const int IN = 128, HID = 256, T = 4, F1 = 64, F2 = 32;
  const int N = in_sizes[0]/IN;
  const int E = in_sizes[1]/2;
  const int NC1 = T*F1;        // 256
  const int NC2 = T*F2;        // 128
  const int LDQ1 = 2*NC1 + NC1;   // 768: [P|Q|postX]
  const int LDQ2 = 2*NC2 + NC2;   // 384

  const float* x      = (const float*)d_in[0];
  const int*   ei     = (const int*)  d_in[1];
  const int*   srcE   = ei;
  const int*   tgtE   = ei + E;
  const float* avgp   = (const float*)d_in[2];
  const float* pre1W  = (const float*)d_in[3];
  const float* pre1b  = (const float*)d_in[4];
  const float* post1W = (const float*)d_in[5];
  const float* post1b = (const float*)d_in[6];
  const float* lin1W  = (const float*)d_in[7];
  const float* lin1b  = (const float*)d_in[8];
  const float* bn1g   = (const float*)d_in[9];
  const float* bn1b   = (const float*)d_in[10];
  const float* pre2W  = (const float*)d_in[11];
  const float* pre2b  = (const float*)d_in[12];
  const float* post2W = (const float*)d_in[13];
  const float* post2b = (const float*)d_in[14];
  const float* lin2W  = (const float*)d_in[15];
  const float* lin2b  = (const float*)d_in[16];
  const float* bn2g   = (const float*)d_in[17];
  const float* bn2b   = (const float*)d_in[18];

  // ---- workspace carve ----
  char* w = (char*)d_ws;
  auto alloc = [&](size_t bytes)->void*{
    void* p = (void*)w; w += (bytes + 255) & ~(size_t)255; return p;
  };
  // combined B^T for pre-GEMM: [WpqT (2*NC rows) | WxT (NC rows)], contiguous
  bf16* BT1    = (bf16*)alloc((size_t)LDQ1*IN*2);
  bf16* WpqT1  = BT1;              bf16* WxT1 = BT1 + (size_t)2*NC1*IN;
  float* bias1 = (float*)alloc((size_t)LDQ1*4);
  float* bpq1  = bias1;            float* bpost1 = bias1 + 2*NC1;
  bf16* Wagg31 = (bf16*)alloc((size_t)T*3*F1*4*F1*2);
  bf16* lin1WT = (bf16*)alloc((size_t)HID*NC1*2);
  bf16* BT2    = (bf16*)alloc((size_t)LDQ2*HID*2);
  bf16* WpqT2  = BT2;              bf16* WxT2 = BT2 + (size_t)2*NC2*HID;
  float* bias2 = (float*)alloc((size_t)LDQ2*4);
  float* bpq2  = bias2;            float* bpost2 = bias2 + 2*NC2;
  bf16* Wagg32 = (bf16*)alloc((size_t)T*3*F2*4*F2*2);
  bf16* lin2WT = (bf16*)alloc((size_t)128*NC2*2);
  // zero region: deg_i | cnt | stats (one memset)
  int* deg_i   = (int*)alloc((size_t)N*4);
  int* cnt     = (int*)alloc((size_t)N*4);
  float* stats = (float*)alloc(1024*4);
  size_t zbytes = (size_t)((char*)stats - (char*)deg_i) + 1024*4;
  int* offs    = (int*)alloc((size_t)(N+1)*4);
  int* bsum    = (int*)alloc((size_t)cdiv(N,256)*4);
  int* ssrc    = (int*)alloc((size_t)E*4);
  bf16* x_bf   = (bf16*)alloc((size_t)N*IN*2);
  bf16* PQX    = (bf16*)alloc((size_t)N*LDQ1*2);   // L2 reuses prefix [N, LDQ2]
  bf16* aggb   = (bf16*)alloc((size_t)N*4*NC1*2);  // L2 reuses prefix [N, 4*NC2]
  float* scal  = (float*)alloc((size_t)N*2*4);
  bf16* postbb = (bf16*)alloc((size_t)N*256*2);
  bf16* hpre   = (bf16*)alloc((size_t)N*256*2);
  bf16* h1b    = (bf16*)alloc((size_t)N*256*2);
  int PB = cdiv(N,128);
  float* part  = (float*)alloc((size_t)PB*512*4);

  hipMemsetAsync(deg_i, 0, zbytes, stream);

  // ---- setup: all weight repacks + x conversion + degree count (one dispatch) ----
  int sgx = cdiv(T*3*F1*4*F1, 256);   // 768 blocks covers the largest segment
  SetupArgs sa = { pre1W, pre1b, post1W, post1b, lin1W,
                   pre2W, pre2b, post2W, post2b, lin2W,
                   x, tgtE,
                   WpqT1, WxT1, Wagg31, lin1WT,
                   WpqT2, WxT2, Wagg32, lin2WT,
                   x_bf, deg_i,
                   bpq1, bpost1, bpq2, bpost2,
                   N*IN/4, E, sgx*256 };
  k_setup<<<dim3(sgx, 10),256,0,stream>>>(sa);

  // ---- counting sort of edges by target (parallel scan) ----
  int NBs = cdiv(N,256);
  k_scan1<<<NBs,256,0,stream>>>(deg_i, bsum, N);
  k_scan2<<<1,1024,0,stream>>>(bsum, NBs);
  k_scan3<<<NBs,256,0,stream>>>(deg_i, bsum, offs, N);
  k_scatter<<<cdiv(E,256),256,0,stream>>>(srcE, tgtE, offs, cnt, ssrc, E);

  int NB = cdiv(N,64);

  // ================= Layer 1 =================
  k_mgemm<bf16><<<dim3(LDQ1/64,NB),256,0,stream>>>(x_bf, IN, BT1, bias1, PQX, LDQ1, N, IN, LDQ1);
  k_agg<256,64><<<cdiv(N,4),256,0,stream>>>(PQX, LDQ1, ssrc, offs, avgp, aggb, scal, N);
  k_postagg<64><<<dim3(1,NB,T),256,0,stream>>>(aggb, Wagg31, PQX, LDQ1, 2*NC1, scal,
                                               postbb, NC1, N);
  k_mgemm<bf16><<<dim3(4,NB),256,0,stream>>>(postbb, NC1, lin1WT, lin1b, hpre, HID, N, NC1, HID);
  k_bn_part<256><<<PB,256,0,stream>>>(hpre, part, N);
  k_bn_final<256><<<dim3(2,4),256,0,stream>>>(part, PB, stats);
  k_bn_apply<bf16,256><<<cdiv(N*64,256),256,0,stream>>>(hpre, stats, bn1g, bn1b, h1b, N);

  // ================= Layer 2 =================
  k_mgemm<bf16><<<dim3(LDQ2/64,NB),256,0,stream>>>(h1b, HID, BT2, bias2, PQX, LDQ2, N, HID, LDQ2);
  k_agg<128,32><<<cdiv(N,4),256,0,stream>>>(PQX, LDQ2, ssrc, offs, avgp, aggb, scal, N);
  k_postagg<32><<<dim3(1,NB,T),256,0,stream>>>(aggb, Wagg32, PQX, LDQ2, 2*NC2, scal,
                                               postbb, NC2, N);
  k_mgemm<bf16><<<dim3(2,NB),256,0,stream>>>(postbb, NC2, lin2WT, lin2b, hpre, 128, N, NC2, 128);
  k_bn_part<128><<<PB,256,0,stream>>>(hpre, part, N);
  k_bn_final<128><<<dim3(1,4),256,0,stream>>>(part, PB, stats + 512);
  k_bn_apply<float,128><<<cdiv(N*32,256),256,0,stream>>>(hpre, stats + 512, bn2g, bn2b, (float*)d_out, N);
}

// Round 16
// 370.610 us; speedup vs baseline: 1.0394x; 1.0306x over previous
//
#include <hip/hip_runtime.h>
#include <hip/hip_bf16.h>
#include <float.h>
#include <math.h>

typedef __hip_bfloat16 bf16;
typedef __attribute__((ext_vector_type(8))) short short8;
typedef __attribute__((ext_vector_type(4))) float f32x4;

__device__ __forceinline__ float bf2f(bf16 v){ return __bfloat162float(v); }
__device__ __forceinline__ void stv(float* p, float v){ *p = v; }
__device__ __forceinline__ void stv(bf16* p, float v){ *p = __float2bfloat16(v); }
__device__ __forceinline__ float nanfix(float v){
  if (v != v) return 0.f;
  return fminf(fmaxf(v, -FLT_MAX), FLT_MAX);
}
__device__ __forceinline__ unsigned short f2bu(float f){
  unsigned u = __float_as_uint(f);
  unsigned r = u + 0x7FFFu + ((u>>16)&1u);
  return (unsigned short)(r>>16);
}
template<int VEC>
__device__ __forceinline__ void ldbf(const bf16* p, float (&o)[VEC]){
  if constexpr (VEC==4){
    ushort4 r = *(const ushort4*)p;
    o[0]=__uint_as_float((unsigned)r.x<<16); o[1]=__uint_as_float((unsigned)r.y<<16);
    o[2]=__uint_as_float((unsigned)r.z<<16); o[3]=__uint_as_float((unsigned)r.w<<16);
  } else {
    ushort2 r = *(const ushort2*)p;
    o[0]=__uint_as_float((unsigned)r.x<<16); o[1]=__uint_as_float((unsigned)r.y<<16);
  }
}

// ---------------- parallel scan + scatter (deg lives in k_setup) ----------------
__global__ void k_scan1(const int* __restrict__ deg, int* __restrict__ bsum, int N){
  __shared__ int sm[256];
  int i = blockIdx.x*256 + threadIdx.x;
  sm[threadIdx.x] = (i < N) ? deg[i] : 0;
  __syncthreads();
  for (int off = 128; off > 0; off >>= 1){
    if (threadIdx.x < off) sm[threadIdx.x] += sm[threadIdx.x + off];
    __syncthreads();
  }
  if (threadIdx.x == 0) bsum[blockIdx.x] = sm[0];
}

__global__ void k_scan2(int* __restrict__ bsum, int NB){
  __shared__ int sm[1024];
  int tid = threadIdx.x;
  sm[tid] = (tid < NB) ? bsum[tid] : 0;
  __syncthreads();
  for (int off = 1; off < 1024; off <<= 1){
    int t = (tid >= off) ? sm[tid-off] : 0;
    __syncthreads();
    sm[tid] += t;
    __syncthreads();
  }
  if (tid < NB) bsum[tid] = (tid == 0) ? 0 : sm[tid-1];   // exclusive block offsets
}

__global__ void k_scan3(const int* __restrict__ deg, const int* __restrict__ bsum,
                        int* __restrict__ offs, int N){
  __shared__ int sm[256];
  int tid = threadIdx.x;
  int i = blockIdx.x*256 + tid;
  int v = (i < N) ? deg[i] : 0;
  sm[tid] = v; __syncthreads();
  for (int off = 1; off < 256; off <<= 1){
    int t = (tid >= off) ? sm[tid-off] : 0;
    __syncthreads();
    sm[tid] += t;
    __syncthreads();
  }
  if (i < N) offs[i+1] = bsum[blockIdx.x] + sm[tid];
  if (i == 0) offs[0] = 0;
}

__global__ void k_scatter(const int* __restrict__ src, const int* __restrict__ tgt,
                          const int* __restrict__ offs, int* __restrict__ cnt,
                          int* __restrict__ ssrc, int E){
  int e = blockIdx.x*blockDim.x + threadIdx.x;
  if (e < E){
    int t = tgt[e];
    int pos = offs[t] + atomicAdd(&cnt[t], 1);
    ssrc[pos] = src[e];
  }
}

// ---------------- fused setup: weight repacks + x conversion + degree count ----------------
__device__ __forceinline__ void rp_pqT(const float* preW, const float* preB,
                                       bf16* WpqT, float* bpq, int K, int F, int idx){
  int NC = 4*F;
  int total = 2*NC*K;
  if (idx < total){
    int j = idx/K, c = idx%K;
    int half = j/NC, jj = j%NC, t = jj/F, f = jj%F;
    WpqT[idx] = __float2bfloat16(preW[(t*2*K + half*K + c)*F + f]);
  }
  if (idx < 2*NC) bpq[idx] = (idx < NC) ? preB[idx] : 0.f;
}
__device__ __forceinline__ void rp_xT(const float* postW, const float* postB,
                                      bf16* WxT, float* bpost, int KX, int F, int idx){
  int NC = 4*F; int KP = KX + 12*F;
  if (idx < NC*KX){
    int j = idx/KX, c = idx%KX, t = j/F, f = j%F;
    WxT[idx] = __float2bfloat16(postW[(t*KP + c)*F + f]);
  }
  if (idx < NC) bpost[idx] = postB[idx];
}
__device__ __forceinline__ void rp_agg3(const float* postW, bf16* Wagg3,
                                        int KX, int F, int idx){
  int K4F = 4*F; int KP = KX + 12*F;
  int total = 4*3*F*K4F;
  if (idx < total){
    int k = idx % K4F; int r = idx / K4F;
    int zr = r % (3*F); int t = r / (3*F);
    int s = zr / F, f = zr % F;
    Wagg3[idx] = __float2bfloat16(postW[((size_t)(t*KP + KX + s*K4F + k))*F + f]);
  }
}
__device__ __forceinline__ void rp_linT(const float* linW, bf16* WlinT,
                                        int K, int NC, int idx){
  if (idx < NC*K){
    int j = idx/K, c = idx%K;
    WlinT[idx] = __float2bfloat16(linW[c*NC + j]);
  }
}

struct SetupArgs {
  const float *pre1W, *pre1b, *post1W, *post1b, *lin1W;
  const float *pre2W, *pre2b, *post2W, *post2b, *lin2W;
  const float *x;
  const int *tgt;
  bf16 *WpqT1, *WxT1, *Wagg31, *lin1WT;
  bf16 *WpqT2, *WxT2, *Wagg32, *lin2WT;
  bf16 *x_bf;
  int *deg;
  float *bpq1, *bpost1, *bpq2, *bpost2;
  int nx4;       // N*IN/4
  int E;
  int gstride;   // gridDim.x*256
};

__global__ void k_setup(SetupArgs a){
  int idx = blockIdx.x*256 + threadIdx.x;
  switch (blockIdx.y){
    case 0: rp_pqT (a.pre1W, a.pre1b, a.WpqT1, a.bpq1, 128, 64, idx); break;
    case 1: rp_xT  (a.post1W, a.post1b, a.WxT1, a.bpost1, 128, 64, idx); break;
    case 2: rp_agg3(a.post1W, a.Wagg31, 128, 64, idx); break;
    case 3: rp_linT(a.lin1W, a.lin1WT, 256, 256, idx); break;
    case 4: rp_pqT (a.pre2W, a.pre2b, a.WpqT2, a.bpq2, 256, 32, idx); break;
    case 5: rp_xT  (a.post2W, a.post2b, a.WxT2, a.bpost2, 256, 32, idx); break;
    case 6: rp_agg3(a.post2W, a.Wagg32, 256, 32, idx); break;
    case 7: rp_linT(a.lin2W, a.lin2WT, 128, 128, idx); break;
    case 8:
      for (int i = idx; i < a.nx4; i += a.gstride){
        float4 v = *(const float4*)(a.x + (size_t)i*4);
        ushort4 o = make_ushort4(f2bu(v.x), f2bu(v.y), f2bu(v.z), f2bu(v.w));
        *(ushort4*)(a.x_bf + (size_t)i*4) = o;
      }
      break;
    case 9:
      for (int e = idx; e < a.E; e += a.gstride)
        atomicAdd(&a.deg[a.tgt[e]], 1);
      break;
  }
}

// ---------------- MFMA GEMM: C[N, *] = A[N,K](bf16) @ Bt[NC,K]^T (bf16) ----------------
// 64x64 tile, 4 waves. STATS: per-column {sum, sumsq} of the output tile -> part[by][2*ldc].
template<typename TO, bool STATS>
__global__ __launch_bounds__(256) void k_mgemm(
    const bf16* __restrict__ A, int lda,
    const bf16* __restrict__ Bt,
    const float* __restrict__ bias,
    TO* __restrict__ Cout, int ldc,
    int N, int K, int NC, float* __restrict__ part)
{
  __shared__ __align__(16) bf16 As[64*40];
  __shared__ __align__(16) bf16 Bs[64*40];
  __shared__ float sstat[4][2][16][2];
  int n0 = blockIdx.y*64;
  int j0 = blockIdx.x*64;
  int tid = threadIdx.x;
  int srow = tid>>2, skoff = (tid&3)*8;
  int wave = tid>>6, lane = tid&63;
  int wy = (wave>>1)*32, wx = (wave&1)*32;
  int l15 = lane&15, q = lane>>4;
  f32x4 acc[2][2] = {};
  for (int k0 = 0; k0 < K; k0 += 32){
    uint4 av = {0,0,0,0};
    int ar = n0 + srow;
    if (ar < N) av = *(const uint4*)(A + (size_t)ar*lda + k0 + skoff);
    *(uint4*)&As[srow*40 + skoff] = av;
    uint4 bv = {0,0,0,0};
    int br = j0 + srow;
    if (br < NC) bv = *(const uint4*)(Bt + (size_t)br*K + k0 + skoff);
    *(uint4*)&Bs[srow*40 + skoff] = bv;
    __syncthreads();
    short8 af[2], bfr[2];
    #pragma unroll
    for (int i = 0; i < 2; i++){
      af[i]  = *(const short8*)&As[(wy + i*16 + l15)*40 + q*8];
      bfr[i] = *(const short8*)&Bs[(wx + i*16 + l15)*40 + q*8];
    }
    #pragma unroll
    for (int mi = 0; mi < 2; mi++)
      #pragma unroll
      for (int ni = 0; ni < 2; ni++)
        acc[mi][ni] = __builtin_amdgcn_mfma_f32_16x16x32_bf16(af[mi], bfr[ni], acc[mi][ni], 0, 0, 0);
    __syncthreads();
  }
  float cs[2] = {0.f, 0.f}, cq[2] = {0.f, 0.f};
  #pragma unroll
  for (int mi = 0; mi < 2; mi++){
    #pragma unroll
    for (int ni = 0; ni < 2; ni++){
      #pragma unroll
      for (int r = 0; r < 4; r++){
        int n  = n0 + wy + mi*16 + q*4 + r;
        int jj = j0 + wx + ni*16 + l15;
        if (n < N && jj < NC){
          float v = acc[mi][ni][r] + bias[jj];
          stv(&Cout[(size_t)n*ldc + jj], v);
          if constexpr (STATS){ cs[ni] += v; cq[ni] = fmaf(v, v, cq[ni]); }
        }
      }
    }
  }
  if constexpr (STATS){
    #pragma unroll
    for (int ni = 0; ni < 2; ni++){
      float s = cs[ni], qq = cq[ni];
      s  += __shfl_xor(s, 16);  s  += __shfl_xor(s, 32);
      qq += __shfl_xor(qq, 16); qq += __shfl_xor(qq, 32);
      if (q == 0){ sstat[wave][ni][l15][0] = s; sstat[wave][ni][l15][1] = qq; }
    }
    __syncthreads();
    if (tid < 64){
      int j = tid;
      int wa = (j < 32) ? 0 : 1, wb = wa + 2;
      int ni = (j & 31) >> 4, li = j & 15;
      float s  = sstat[wa][ni][li][0] + sstat[wb][ni][li][0];
      float qq = sstat[wa][ni][li][1] + sstat[wb][ni][li][1];
      part[(size_t)blockIdx.y*2*ldc + (j0 + j)]       = s;
      part[(size_t)blockIdx.y*2*ldc + ldc + (j0 + j)] = qq;
    }
  }
}

// ---------------- post-agg GEMM (phase-2 only): Cin (x@Wx+bias, bf16) read from PQX ----------------
template<int COLS>
__global__ __launch_bounds__(256) void k_postagg(
    const bf16* __restrict__ agg,      // [N, 16*COLS]
    const bf16* __restrict__ Wagg3,    // [T][3*COLS][K4F]
    const bf16* __restrict__ PQX, int ldq, int cinOff,
    const float* __restrict__ scal,
    bf16* __restrict__ Cout, int ldc, int N)
{
  constexpr int K4F = 4*COLS;
  constexpr int ROWS3 = 3*COLS;
  constexpr int NI = COLS/32;          // 2 (COLS=64) or 1 (COLS=32)
  constexpr int LDA_AGG = 16*COLS;
  __shared__ __align__(16) bf16 As[64*40];
  __shared__ __align__(16) bf16 Bs[ROWS3*40];
  int z = blockIdx.z;
  int n0 = blockIdx.y*64;
  int tid = threadIdx.x;
  int srow = tid>>2, skoff = (tid&3)*8;
  int wave = tid>>6, lane = tid&63;
  int wy = (wave>>1)*32;
  int wx = (wave&1)*(COLS/2);
  int l15 = lane&15, q = lane>>4;
  f32x4 acc[2][NI][3] = {};
  const bf16* Az = agg + (size_t)z*K4F;
  const bf16* Bz = Wagg3 + (size_t)z*ROWS3*K4F;
  for (int k0 = 0; k0 < K4F; k0 += 32){
    uint4 av = {0,0,0,0};
    int ar = n0 + srow;
    if (ar < N) av = *(const uint4*)(Az + (size_t)ar*LDA_AGG + k0 + skoff);
    *(uint4*)&As[srow*40 + skoff] = av;
    for (int r = srow; r < ROWS3; r += 64){
      uint4 bv = *(const uint4*)(Bz + (size_t)r*K4F + k0 + skoff);
      *(uint4*)&Bs[r*40 + skoff] = bv;
    }
    __syncthreads();
    short8 af[2];
    #pragma unroll
    for (int i = 0; i < 2; i++)
      af[i] = *(const short8*)&As[(wy + i*16 + l15)*40 + q*8];
    #pragma unroll
    for (int s = 0; s < 3; s++){
      #pragma unroll
      for (int ni = 0; ni < NI; ni++){
        short8 bfr = *(const short8*)&Bs[(s*COLS + wx + ni*16 + l15)*40 + q*8];
        #pragma unroll
        for (int mi = 0; mi < 2; mi++)
          acc[mi][ni][s] = __builtin_amdgcn_mfma_f32_16x16x32_bf16(af[mi], bfr, acc[mi][ni][s], 0, 0, 0);
      }
    }
    __syncthreads();
  }
  #pragma unroll
  for (int mi = 0; mi < 2; mi++){
    #pragma unroll
    for (int ni = 0; ni < NI; ni++){
      int jj = wx + ni*16 + l15;
      int jg = z*COLS + jj;
      #pragma unroll
      for (int r = 0; r < 4; r++){
        int n = n0 + wy + mi*16 + q*4 + r;
        if (n < N){
          float s1 = scal[2*n], s2 = scal[2*n+1];
          float cin = bf2f(PQX[(size_t)n*ldq + cinOff + jg]);
          float v = cin + acc[mi][ni][0][r] + s1*acc[mi][ni][1][r] + s2*acc[mi][ni][2][r];
          Cout[(size_t)n*ldc + jg] = __float2bfloat16(v);
        }
      }
    }
  }
}

// ---------------- per-node PNA aggregation -> agg [N, T*4F] bf16 + scal ----------------
template<int NC, int F>
__global__ __launch_bounds__(256) void k_agg(const bf16* __restrict__ PQ, int lda,
    const int* __restrict__ ssrc, const int* __restrict__ offs,
    const float* __restrict__ avgp,
    bf16* __restrict__ agg, float* __restrict__ scal, int N){
  constexpr int VEC = NC/64;
  int wave = threadIdx.x>>6, lane = threadIdx.x&63;
  int n = blockIdx.x*4 + wave;
  if (n >= N) return;
  int c0 = lane*VEC;
  float p[VEC];
  ldbf<VEC>(PQ + (size_t)n*lda + c0, p);
  int s0 = offs[n], s1 = offs[n+1];
  float sum[VEC], sq[VEC], mn[VEC], mx[VEC];
  #pragma unroll
  for (int v=0;v<VEC;v++){ sum[v]=0.f; sq[v]=0.f; mn[v]=FLT_MAX; mx[v]=-FLT_MAX; }
  const bf16* Q = PQ + NC + c0;
  int i = s0;
  for (; i+7 < s1; i += 8){
    int se[8];
    #pragma unroll
    for (int u=0;u<8;u++) se[u] = ssrc[i+u];
    float qv[8][VEC];
    #pragma unroll
    for (int u=0;u<8;u++) ldbf<VEC>(Q + (size_t)se[u]*lda, qv[u]);
    #pragma unroll
    for (int u=0;u<8;u++){
      #pragma unroll
      for (int v=0;v<VEC;v++){
        float qq = qv[u][v];
        sum[v] += qq; sq[v] = fmaf(qq,qq,sq[v]);
        mn[v] = fminf(mn[v], qq); mx[v] = fmaxf(mx[v], qq);
      }
    }
  }
  for (; i+3 < s1; i += 4){
    int se[4];
    #pragma unroll
    for (int u=0;u<4;u++) se[u] = ssrc[i+u];
    float qv[4][VEC];
    #pragma unroll
    for (int u=0;u<4;u++) ldbf<VEC>(Q + (size_t)se[u]*lda, qv[u]);
    #pragma unroll
    for (int u=0;u<4;u++){
      #pragma unroll
      for (int v=0;v<VEC;v++){
        float qq = qv[u][v];
        sum[v] += qq; sq[v] = fmaf(qq,qq,sq[v]);
        mn[v] = fminf(mn[v], qq); mx[v] = fmaxf(mx[v], qq);
      }
    }
  }
  for (; i < s1; i++){
    int sa = ssrc[i];
    float qa[VEC];
    ldbf<VEC>(Q + (size_t)sa*lda, qa);
    #pragma unroll
    for (int v=0;v<VEC;v++){
      float qq = qa[v];
      sum[v]+=qq; sq[v]=fmaf(qq,qq,sq[v]); mn[v]=fminf(mn[v],qq); mx[v]=fmaxf(mx[v],qq);
    }
  }
  int deg = s1-s0;
  float degf = (float)deg;
  float degc = fmaxf(degf, 1.f);
  unsigned short um[VEC], un[VEC], ux[VEC], us[VEC];
  #pragma unroll
  for (int v=0;v<VEC;v++){
    float pv = p[v];
    float sum_m = fmaf(degf, pv, sum[v]);
    float sq_m  = sq[v] + 2.f*pv*sum[v] + degf*pv*pv;
    float mean = sum_m/degc;
    float var = fmaxf(sq_m/degc - mean*mean, 0.f);
    float sd = sqrtf(var + 1e-5f);
    float mnv = deg>0 ? pv + mn[v] : 0.f;
    float mxv = deg>0 ? pv + mx[v] : 0.f;
    um[v]=f2bu(mean); un[v]=f2bu(mnv); ux[v]=f2bu(mxv); us[v]=f2bu(sd);
  }
  int t = c0 / F, f0 = c0 % F;
  bf16* base = agg + (size_t)n*4*NC + (size_t)t*4*F + f0;
  if constexpr (VEC==4){
    *(ushort4*)(base)       = make_ushort4(um[0],um[1],um[2],um[3]);
    *(ushort4*)(base + F)   = make_ushort4(un[0],un[1],un[2],un[3]);
    *(ushort4*)(base + 2*F) = make_ushort4(ux[0],ux[1],ux[2],ux[3]);
    *(ushort4*)(base + 3*F) = make_ushort4(us[0],us[1],us[2],us[3]);
  } else {
    *(ushort2*)(base)       = make_ushort2(um[0],um[1]);
    *(ushort2*)(base + F)   = make_ushort2(un[0],un[1]);
    *(ushort2*)(base + 2*F) = make_ushort2(ux[0],ux[1]);
    *(ushort2*)(base + 3*F) = make_ushort2(us[0],us[1]);
  }
  if (lane==0){
    float dlog = logf(degc + 1.f);
    float avg = *avgp;
    scal[2*n]   = dlog/avg;
    scal[2*n+1] = avg/dlog;
  }
}

// ---------------- batch norm: final reduce + apply ----------------
template<int C>
__global__ __launch_bounds__(256) void k_bn_final(const float* __restrict__ part, int PB,
                                                  float* __restrict__ stats){
  int c = blockIdx.x*256 + threadIdx.x;
  if (c >= 2*C) return;
  int CH = gridDim.y;
  int per = (PB + CH - 1)/CH;
  int p0 = blockIdx.y*per, p1 = min(p0 + per, PB);
  float acc = 0.f;
  int p = p0;
  for (; p+4 <= p1; p += 4){
    acc += part[(size_t)p*2*C + c] + part[(size_t)(p+1)*2*C + c]
         + part[(size_t)(p+2)*2*C + c] + part[(size_t)(p+3)*2*C + c];
  }
  for (; p < p1; p++) acc += part[(size_t)p*2*C + c];
  atomicAdd(&stats[c], acc);
}

template<typename TO, int C>
__global__ void k_bn_apply(const bf16* __restrict__ h, const float* __restrict__ stats,
     const float* __restrict__ g, const float* __restrict__ b,
     TO* __restrict__ out, int N){
  int idx = blockIdx.x*blockDim.x + threadIdx.x;   // quad index
  if (idx >= N*(C/4)) return;
  int c = (idx % (C/4))*4;
  float fn = (float)N;
  float v[4];
  ldbf<4>(h + (size_t)idx*4, v);
  float r[4];
  #pragma unroll
  for (int k = 0; k < 4; k++){
    float m = stats[c+k]/fn;
    float var = fmaxf(stats[C+c+k]/fn - m*m, 0.f);
    float inv = rsqrtf(var + 1e-5f);
    float vv = nanfix(v[k]);
    r[k] = fmaxf(g[c+k]*(vv - m)*inv + b[c+k], 0.f);
  }
  if constexpr (sizeof(TO) == 4){
    float4 o = {r[0], r[1], r[2], r[3]};
    *(float4*)((float*)out + (size_t)idx*4) = o;
  } else {
    ushort4 o = make_ushort4(f2bu(r[0]), f2bu(r[1]), f2bu(r[2]), f2bu(r[3]));
    *(ushort4*)((bf16*)out + (size_t)idx*4) = o;
  }
}

static inline int cdiv(int a, int b){ return (a + b - 1)/b; }

extern "C" void kernel_launch(void* const* d_in, const int* in_sizes, int n_in,
                              void* d_out, int out_size, void* d_ws, size_t ws_size,
                              hipStream_t stream){
  const int IN = 128, HID = 256, T = 4, F1 = 64, F2 = 32;
  const int N = in_sizes[0]/IN;
  const int E = in_sizes[1]/2;
  const int NC1 = T*F1;        // 256
  const int NC2 = T*F2;        // 128
  const int LDQ1 = 2*NC1 + NC1;   // 768: [P|Q|postX]
  const int LDQ2 = 2*NC2 + NC2;   // 384

  const float* x      = (const float*)d_in[0];
  const int*   ei     = (const int*)  d_in[1];
  const int*   srcE   = ei;
  const int*   tgtE   = ei + E;
  const float* avgp   = (const float*)d_in[2];
  const float* pre1W  = (const float*)d_in[3];
  const float* pre1b  = (const float*)d_in[4];
  const float* post1W = (const float*)d_in[5];
  const float* post1b = (const float*)d_in[6];
  const float* lin1W  = (const float*)d_in[7];
  const float* lin1b  = (const float*)d_in[8];
  const float* bn1g   = (const float*)d_in[9];
  const float* bn1b   = (const float*)d_in[10];
  const float* pre2W  = (const float*)d_in[11];
  const float* pre2b  = (const float*)d_in[12];
  const float* post2W = (const float*)d_in[13];
  const float* post2b = (const float*)d_in[14];
  const float* lin2W  = (const float*)d_in[15];
  const float* lin2b  = (const float*)d_in[16];
  const float* bn2g   = (const float*)d_in[17];
  const float* bn2b   = (const float*)d_in[18];

  // ---- workspace carve ----
  char* w = (char*)d_ws;
  auto alloc = [&](size_t bytes)->void*{
    void* p = (void*)w; w += (bytes + 255) & ~(size_t)255; return p;
  };
  // combined B^T for pre-GEMM: [WpqT (2*NC rows) | WxT (NC rows)], contiguous
  bf16* BT1    = (bf16*)alloc((size_t)LDQ1*IN*2);
  bf16* WpqT1  = BT1;              bf16* WxT1 = BT1 + (size_t)2*NC1*IN;
  float* bias1 = (float*)alloc((size_t)LDQ1*4);
  float* bpq1  = bias1;            float* bpost1 = bias1 + 2*NC1;
  bf16* Wagg31 = (bf16*)alloc((size_t)T*3*F1*4*F1*2);
  bf16* lin1WT = (bf16*)alloc((size_t)HID*NC1*2);
  bf16* BT2    = (bf16*)alloc((size_t)LDQ2*HID*2);
  bf16* WpqT2  = BT2;              bf16* WxT2 = BT2 + (size_t)2*NC2*HID;
  float* bias2 = (float*)alloc((size_t)LDQ2*4);
  float* bpq2  = bias2;            float* bpost2 = bias2 + 2*NC2;
  bf16* Wagg32 = (bf16*)alloc((size_t)T*3*F2*4*F2*2);
  bf16* lin2WT = (bf16*)alloc((size_t)128*NC2*2);
  // zero region: deg_i | cnt | stats (one memset)
  int* deg_i   = (int*)alloc((size_t)N*4);
  int* cnt     = (int*)alloc((size_t)N*4);
  float* stats = (float*)alloc(1024*4);
  size_t zbytes = (size_t)((char*)stats - (char*)deg_i) + 1024*4;
  int* offs    = (int*)alloc((size_t)(N+1)*4);
  int* bsum    = (int*)alloc((size_t)cdiv(N,256)*4);
  int* ssrc    = (int*)alloc((size_t)E*4);
  bf16* x_bf   = (bf16*)alloc((size_t)N*IN*2);
  bf16* PQX    = (bf16*)alloc((size_t)N*LDQ1*2);   // L2 reuses prefix [N, LDQ2]
  bf16* aggb   = (bf16*)alloc((size_t)N*4*NC1*2);  // L2 reuses prefix [N, 4*NC2]
  float* scal  = (float*)alloc((size_t)N*2*4);
  bf16* postbb = (bf16*)alloc((size_t)N*256*2);
  bf16* hpre   = (bf16*)alloc((size_t)N*256*2);
  bf16* h1b    = (bf16*)alloc((size_t)N*256*2);
  int NB = cdiv(N,64);
  float* part  = (float*)alloc((size_t)NB*512*4);

  hipMemsetAsync(deg_i, 0, zbytes, stream);

  // ---- setup: all weight repacks + x conversion + degree count (one dispatch) ----
  int sgx = cdiv(T*3*F1*4*F1, 256);   // 768 blocks covers the largest segment
  SetupArgs sa = { pre1W, pre1b, post1W, post1b, lin1W,
                   pre2W, pre2b, post2W, post2b, lin2W,
                   x, tgtE,
                   WpqT1, WxT1, Wagg31, lin1WT,
                   WpqT2, WxT2, Wagg32, lin2WT,
                   x_bf, deg_i,
                   bpq1, bpost1, bpq2, bpost2,
                   N*IN/4, E, sgx*256 };
  k_setup<<<dim3(sgx, 10),256,0,stream>>>(sa);

  // ---- counting sort of edges by target (parallel scan) ----
  int NBs = cdiv(N,256);
  k_scan1<<<NBs,256,0,stream>>>(deg_i, bsum, N);
  k_scan2<<<1,1024,0,stream>>>(bsum, NBs);
  k_scan3<<<NBs,256,0,stream>>>(deg_i, bsum, offs, N);
  k_scatter<<<cdiv(E,256),256,0,stream>>>(srcE, tgtE, offs, cnt, ssrc, E);

  // ================= Layer 1 =================
  k_mgemm<bf16,false><<<dim3(LDQ1/64,NB),256,0,stream>>>(x_bf, IN, BT1, bias1, PQX, LDQ1, N, IN, LDQ1, nullptr);
  k_agg<256,64><<<cdiv(N,4),256,0,stream>>>(PQX, LDQ1, ssrc, offs, avgp, aggb, scal, N);
  k_postagg<64><<<dim3(1,NB,T),256,0,stream>>>(aggb, Wagg31, PQX, LDQ1, 2*NC1, scal,
                                               postbb, NC1, N);
  k_mgemm<bf16,true><<<dim3(4,NB),256,0,stream>>>(postbb, NC1, lin1WT, lin1b, hpre, HID, N, NC1, HID, part);
  k_bn_final<256><<<dim3(2,4),256,0,stream>>>(part, NB, stats);
  k_bn_apply<bf16,256><<<cdiv(N*64,256),256,0,stream>>>(hpre, stats, bn1g, bn1b, h1b, N);

  // ================= Layer 2 =================
  k_mgemm<bf16,false><<<dim3(LDQ2/64,NB),256,0,stream>>>(h1b, HID, BT2, bias2, PQX, LDQ2, N, HID, LDQ2, nullptr);
  k_agg<128,32><<<cdiv(N,4),256,0,stream>>>(PQX, LDQ2, ssrc, offs, avgp, aggb, scal, N);
  k_postagg<32><<<dim3(1,NB,T),256,0,stream>>>(aggb, Wagg32, PQX, LDQ2, 2*NC2, scal,
                                               postbb, NC2, N);
  k_mgemm<bf16,true><<<dim3(2,NB),256,0,stream>>>(postbb, NC2, lin2WT, lin2b, hpre, 128, N, NC2, 128, part);
  k_bn_final<128><<<dim3(1,4),256,0,stream>>>(part, NB, stats + 512);
  k_bn_apply<float,128><<<cdiv(N*32,256),256,0,stream>>>(hpre, stats + 512, bn2g, bn2b, (float*)d_out, N);
}